// Round 11
// baseline (462.947 us; speedup 1.0000x reference)
//
#include <hip/hip_runtime.h>

typedef float f32x4 __attribute__((ext_vector_type(4)));
typedef unsigned int uint32;

#define MAXV 51200            // bitmap capacity; V=50257 fits
#define NWMAX (MAXV / 32 + 1) // 1601 words (+1 pad for spanning reads)
#define LPAD 1024             // sorted-list capacity (L=400 fits)

// ---------------------------------------------------------------------------
// Prep: per source column b, sort (v, l) pairs ascending by (v, l) via O(L^2)
// rank sort. Row-independent (rows share columns mod B). Last-occurrence-wins
// falls out of upper_bound search later (max l sorts last among equal v).
// ---------------------------------------------------------------------------
__global__ __launch_bounds__(256) void sort_kernel(
    const int* __restrict__ sources, int* __restrict__ sv, int* __restrict__ sl,
    int L, int B, int V)
{
    const int b = blockIdx.x;
    __shared__ int s_col[LPAD];
    for (int l = threadIdx.x; l < L; l += 256) {
        const int v = sources[(size_t)l * B + b];
        s_col[l] = (v >= 0 && v < V) ? v : 0x7FFFFFFF;   // mode="drop"
    }
    __syncthreads();
    int* __restrict__ svb = sv + (size_t)b * L;
    int* __restrict__ slb = sl + (size_t)b * L;
    for (int l = threadIdx.x; l < L; l += 256) {
        const int v = s_col[l];
        int rank = 0;
        for (int k = 0; k < L; ++k) {
            const int vk = s_col[k];
            rank += (vk < v) || (vk == v && k < l);
        }
        svb[rank] = v;
        slb[rank] = l;
    }
}

// ---------------------------------------------------------------------------
// Fused single-pass (R6 structure, best: 234us). 2x2 cache-flag factorial:
// NTL = nontemporal (L2/L3-bypass-ish) loads, NTS = nontemporal stores.
// Four dispatches, one per quadrant, each owning rows [r0, r0+nrows).
// Same stream => serialized => per-dispatch rocprof timings give a clean
// within-probe A/B of the memory-path policy.
// ---------------------------------------------------------------------------
template <bool NTL, bool NTS>
__global__ __launch_bounds__(256) void fused_kernel(
    const float* __restrict__ vd, const float* __restrict__ attns,
    const float* __restrict__ pgs, const int* __restrict__ sv,
    const int* __restrict__ sl, float* __restrict__ out, int V, int L, int B,
    int r0)
{
    const int row = blockIdx.x + r0;
    const int tid = threadIdx.x;
    const int b   = row % B;

    __shared__ uint32 bm[NWMAX];
    __shared__ int    s_v[LPAD];
    __shared__ int    s_l[LPAD];
    __shared__ float  s_attn[LPAD];

    const int NW = (V + 31) >> 5;
    for (int w = tid; w < NW + 1; w += 256) bm[w] = 0u;
    const int* __restrict__ svb = sv + (size_t)b * L;
    const int* __restrict__ slb = sl + (size_t)b * L;
    for (int t = tid; t < LPAD; t += 256) {
        s_v[t]    = (t < L) ? svb[t] : 0x7FFFFFFF;
        s_l[t]    = (t < L) ? slb[t] : 0;
        s_attn[t] = (t < L) ? attns[(size_t)row * L + t] : 0.0f;
    }
    __syncthreads();
    for (int t = tid; t < L; t += 256) {
        const int v = s_v[t];
        if (v < V) atomicOr(&bm[v >> 5], 1u << (v & 31));
    }
    __syncthreads();

    const float pg   = pgs[row];
    const float gate = 1.0f - pg;
    const size_t base = (size_t)row * (size_t)V;

    // upper_bound(j) - 1 => last entry with s_v==j => max l => last-wins
    auto lookup = [&](int j) -> float {
        int lo = 0, hi = LPAD;
        while (lo < hi) {
            const int mid = (lo + hi) >> 1;
            if (s_v[mid] <= j) lo = mid + 1; else hi = mid;
        }
        return gate * s_attn[s_l[lo - 1]];
    };

    auto store1 = [&](float x, float* p) {
        if (NTS) __builtin_nontemporal_store(x, p);
        else     *p = x;
    };
    auto store4 = [&](f32x4 x, f32x4* p) {
        if (NTS) __builtin_nontemporal_store(x, p);
        else     *p = x;
    };

    // peel to 16B alignment (V odd -> base mod 4 rotates per row)
    const int mis  = (int)(base & 3);
    const int pre  = mis ? (4 - mis) : 0;
    const int preN = pre < V ? pre : V;
    if (tid < preN) {
        const int j = tid;
        float x = pg * vd[base + j];
        if ((bm[j >> 5] >> (j & 31)) & 1u) x += lookup(j);
        store1(x, &out[base + j]);
    }

    const int nvec = (V - preN) >> 2;
    const f32x4* __restrict__ v4 = (const f32x4*)(vd + base + preN);
    f32x4* __restrict__ o4       = (f32x4*)(out + base + preN);

    auto proc = [&](int i) {
        f32x4 x = NTL ? __builtin_nontemporal_load(&v4[i]) : v4[i];
        x *= pg;
        const int j0 = preN + (i << 2);
        const int w  = j0 >> 5;
        const uint32 sh = (uint32)(j0 & 31);
        uint32 bits;
        if (sh <= 28u) bits = (bm[w] >> sh) & 0xFu;
        else           bits = ((bm[w] >> sh) | (bm[w + 1] << (32u - sh))) & 0xFu;
        if (bits) {
#pragma unroll
            for (int e = 0; e < 4; ++e)
                if ((bits >> e) & 1u) x[e] += lookup(j0 + e);
        }
        store4(x, &o4[i]);
    };

    int i = tid;
    for (; i + 768 < nvec; i += 1024) {
        proc(i); proc(i + 256); proc(i + 512); proc(i + 768);
    }
    for (; i < nvec; i += 256) proc(i);

    for (int j = preN + (nvec << 2) + tid; j < V; j += 256) {
        float x = pg * vd[base + j];
        if ((bm[j >> 5] >> (j & 31)) & 1u) x += lookup(j);
        store1(x, &out[base + j]);
    }
}

// ---------------------------------------------------------------------------
// Fallback (round-1 fused kernel, verified correct) if ws/V/L out of bounds.
// ---------------------------------------------------------------------------
__global__ __launch_bounds__(256) void fused_fallback_kernel(
    const float* __restrict__ vocab_ds, const float* __restrict__ attns,
    const float* __restrict__ p_gens, const int* __restrict__ sources,
    float* __restrict__ out, int V, int L, int B)
{
    const int row = blockIdx.x;
    const int tid = threadIdx.x;
    const size_t base = (size_t)row * (size_t)V;
    const float pg = p_gens[row];

    const int mis  = (int)(base & 3);
    const int pre  = mis ? (4 - mis) : 0;
    const int preN = pre < V ? pre : V;
    for (int j = tid; j < preN; j += blockDim.x)
        out[base + j] = pg * vocab_ds[base + j];
    const int nvec = (V - preN) >> 2;
    const f32x4* __restrict__ v4 = (const f32x4*)(vocab_ds + base + preN);
    f32x4* __restrict__ o4       = (f32x4*)(out + base + preN);
    for (int i = tid; i < nvec; i += blockDim.x) {
        f32x4 x = v4[i];
        x *= pg;
        o4[i] = x;
    }
    for (int j = preN + (nvec << 2) + tid; j < V; j += blockDim.x)
        out[base + j] = pg * vocab_ds[base + j];

    __shared__ int s_src[512];
    const int b = row % B;
    const bool use_lds = (L <= 512);
    if (use_lds) {
        for (int l = tid; l < L; l += blockDim.x)
            s_src[l] = sources[(size_t)l * B + b];
    }
    __syncthreads();
    const float gate = 1.0f - pg;
    for (int l = tid; l < L; l += blockDim.x) {
        const int v = use_lds ? s_src[l] : sources[(size_t)l * B + b];
        if (v < 0 || v >= V) continue;
        bool last = true;
        for (int l2 = l + 1; l2 < L; ++l2) {
            const int v2 = use_lds ? s_src[l2] : sources[(size_t)l2 * B + b];
            if (v2 == v) { last = false; break; }
        }
        if (last) {
            const float a = gate * attns[(size_t)row * L + l];
            out[base + v] = pg * vocab_ds[base + v] + a;
        }
    }
}

extern "C" void kernel_launch(void* const* d_in, const int* in_sizes, int n_in,
                              void* d_out, int out_size, void* d_ws, size_t ws_size,
                              hipStream_t stream) {
    const float* vocab_ds = (const float*)d_in[0];
    const float* attns    = (const float*)d_in[1];
    const float* p_gens   = (const float*)d_in[2];
    const int*   sources  = (const int*)d_in[3];
    const int rows = in_sizes[2];
    const int V    = in_sizes[0] / rows;
    const int L    = in_sizes[1] / rows;
    const int B    = in_sizes[3] / L;
    float* out = (float*)d_out;

    const size_t need = (size_t)B * (size_t)L * 2 * sizeof(int);
    const bool fits = (ws_size >= need) && (V <= (NWMAX - 1) * 32) && (L <= LPAD);
    if (fits) {
        int* sv = (int*)d_ws;
        int* sl = sv + (size_t)B * (size_t)L;
        sort_kernel<<<B, 256, 0, stream>>>(sources, sv, sl, L, B, V);

        const int q = rows / 4;
        // launch order (Dispatch_Id ascending): NTL,NTS -> NTL,- -> -,NTS -> -,-
        if (q > 0) {
            fused_kernel<true,  true ><<<q, 256, 0, stream>>>(
                vocab_ds, attns, p_gens, sv, sl, out, V, L, B, 0);
            fused_kernel<true,  false><<<q, 256, 0, stream>>>(
                vocab_ds, attns, p_gens, sv, sl, out, V, L, B, q);
            fused_kernel<false, true ><<<q, 256, 0, stream>>>(
                vocab_ds, attns, p_gens, sv, sl, out, V, L, B, 2 * q);
        }
        fused_kernel<false, false><<<rows - 3 * q, 256, 0, stream>>>(
            vocab_ds, attns, p_gens, sv, sl, out, V, L, B, 3 * q);
    } else {
        fused_fallback_kernel<<<rows, 256, 0, stream>>>(
            vocab_ds, attns, p_gens, sources, out, V, L, B);
    }
}

// Round 12
// 237.935 us; speedup vs baseline: 1.9457x; 1.9457x over previous
//
#include <hip/hip_runtime.h>

typedef float f32x4 __attribute__((ext_vector_type(4)));
typedef unsigned int uint32;
typedef unsigned short ushort16;

#define MAXV 51200            // bitmap capacity; V=50257 fits
#define NWMAX (MAXV / 32 + 1) // 1601 words (+1 pad for spanning reads)
#define LPAD 1024             // sort staging (L=400 fits)
#define LP2 512               // in-kernel sorted-list capacity (binary search)
#define WCH 512               // floats per wave-chunk (2 KB)

// ---------------------------------------------------------------------------
// Prep: per source column b, sort (v, l) pairs ascending by (v, l) via O(L^2)
// rank sort. Row-independent (rows share columns mod B). Last-occurrence-wins
// falls out of upper_bound search later (max l sorts last among equal v).
// ---------------------------------------------------------------------------
__global__ __launch_bounds__(256) void sort_kernel(
    const int* __restrict__ sources, int* __restrict__ sv, int* __restrict__ sl,
    int L, int B, int V)
{
    const int b = blockIdx.x;
    __shared__ int s_col[LPAD];
    for (int l = threadIdx.x; l < L; l += 256) {
        const int v = sources[(size_t)l * B + b];
        s_col[l] = (v >= 0 && v < V) ? v : 0x7FFFFFFF;   // mode="drop"
    }
    __syncthreads();
    int* __restrict__ svb = sv + (size_t)b * L;
    int* __restrict__ slb = sl + (size_t)b * L;
    for (int l = threadIdx.x; l < L; l += 256) {
        const int v = s_col[l];
        int rank = 0;
        for (int k = 0; k < L; ++k) {
            const int vk = s_col[k];
            rank += (vk < v) || (vk == v && k < l);
        }
        svb[rank] = v;
        slb[rank] = l;
    }
}

// ---------------------------------------------------------------------------
// Fused single-pass with global_load_lds DMA streaming.
// Per block (one row, 4 waves): wave w owns chunks g = k*4+w (2 KB each),
// double-buffered through wave-private LDS. 2 DMA issues/chunk; counted
// s_waitcnt vmcnt(4) keeps next-chunk loads + prior stores in flight
// (in-order vmcnt retirement guarantees current chunk landed). The DMA has
// no destination register, so the compiler cannot collapse the pipeline
// (R7/R8/R10: every register-based attempt was folded back to MLP~1).
// ---------------------------------------------------------------------------
__global__ __launch_bounds__(256) void fused_kernel(
    const float* __restrict__ vd, const float* __restrict__ attns,
    const float* __restrict__ pgs, const int* __restrict__ sv,
    const int* __restrict__ sl, float* __restrict__ out, int V, int L, int B)
{
    const int row  = blockIdx.x;
    const int tid  = threadIdx.x;
    const int wid  = tid >> 6;
    const int lane = tid & 63;
    const int b    = row % B;

    __shared__ __align__(16) float stage[4][2][WCH];   // 16 KB staging
    __shared__ uint32    bm[NWMAX];                    // 6.4 KB bitmap
    __shared__ ushort16  s_v[LP2];                     // 1 KB sorted ids
    __shared__ float     s_attn[LP2];                  // 2 KB rank-gathered

    const int NW = (V + 31) >> 5;
    for (int w = tid; w < NW + 1; w += 256) bm[w] = 0u;
    const int* __restrict__ svb = sv + (size_t)b * L;
    const int* __restrict__ slb = sl + (size_t)b * L;
    for (int t = tid; t < LP2; t += 256) {
        int v = 0xFFFF; float a = 0.0f;
        if (t < L) {
            const int vv = svb[t];
            v = (vv > 0xFFFF) ? 0xFFFF : vv;           // dropped ids -> sentinel
            a = attns[(size_t)row * L + slb[t]];
        }
        s_v[t]    = (ushort16)v;
        s_attn[t] = a;
    }
    __syncthreads();
    for (int t = tid; t < L; t += 256) {
        const int v = svb[t];
        if (v >= 0 && v < V) atomicOr(&bm[v >> 5], 1u << (v & 31));
    }
    __syncthreads();

    const float pg   = pgs[row];
    const float gate = 1.0f - pg;
    const size_t base = (size_t)row * (size_t)V;

    // last t with s_v[t] <= j  (bit set guarantees a match; sentinel > any j)
    auto lookup = [&](int j) -> float {
        int lo = 0, hi = LP2;
        while (lo < hi) {
            const int mid = (lo + hi) >> 1;
            if ((int)s_v[mid] <= j) lo = mid + 1; else hi = mid;
        }
        return gate * s_attn[lo - 1];
    };

    // finish one f32x4 whose global column base is j0; store to p
    auto finish = [&](f32x4 x, int j0, f32x4* p) {
        x *= pg;
        const int w  = j0 >> 5;
        const uint32 sh = (uint32)(j0 & 31);
        uint32 bits = bm[w] >> sh;
        if (sh > 28u) bits |= bm[w + 1] << (32u - sh);
        bits &= 0xFu;
        if (bits) {
#pragma unroll
            for (int e = 0; e < 4; ++e)
                if ((bits >> e) & 1u) x[e] += lookup(j0 + e);
        }
        __builtin_nontemporal_store(x, p);
    };

    // peel to 16B alignment (V odd -> base mod 4 rotates per row)
    const int mis  = (int)(base & 3);
    const int pre  = mis ? (4 - mis) : 0;
    const int preN = pre < V ? pre : V;
    if (tid < preN) {
        const int j = tid;
        float x = pg * vd[base + j];
        if ((bm[j >> 5] >> (j & 31)) & 1u) x += lookup(j);
        __builtin_nontemporal_store(x, &out[base + j]);
    }

    const float* rsrc = vd + base + preN;     // 16B-aligned
    float*       rdst = out + base + preN;    // 16B-aligned
    const int navail = V - preN;
    const int nal    = navail & ~(4 * WCH - 1);   // floats covered by pipeline
    const int nk     = nal >> 11;                  // chunks per wave

    if (nk > 0) {
        float* buf0 = &stage[wid][0][0];
        float* buf1 = &stage[wid][1][0];

        auto issue = [&](float* lbuf, int k, bool real) {
            const float* g = real ? (rsrc + (((size_t)(k * 4 + wid)) << 9))
                                  : rsrc;          // dummy keeps vmcnt uniform
            __builtin_amdgcn_global_load_lds(g + (lane << 2),        lbuf,       16, 0, 0);
            __builtin_amdgcn_global_load_lds(g + (lane << 2) + 256,  lbuf + 256, 16, 0, 0);
        };
        auto consume = [&](const float* lbuf, int k) {
            const int f0 = ((k * 4 + wid) << 9) + (lane << 2);
            f32x4 x0 = *(const f32x4*)&lbuf[lane << 2];
            f32x4 x1 = *(const f32x4*)&lbuf[(lane << 2) + 256];
            finish(x0, preN + f0,       (f32x4*)(rdst + f0));
            finish(x1, preN + f0 + 256, (f32x4*)(rdst + f0 + 256));
        };

        issue(buf0, 0, true);
        issue(buf1, 1, nk > 1);
        asm volatile("s_waitcnt vmcnt(2)" ::: "memory");   // buf0 landed
        __builtin_amdgcn_sched_barrier(0);
        consume(buf0, 0);
        for (int k = 1; k < nk; ++k) {
            float* bufc = (k & 1) ? buf1 : buf0;
            float* bufn = (k & 1) ? buf0 : buf1;
            issue(bufn, k + 1, k + 1 < nk);
            // newer than chunk-k loads: 2 stores(k-1) + 2 loads(k+1) = 4
            asm volatile("s_waitcnt vmcnt(4)" ::: "memory");
            __builtin_amdgcn_sched_barrier(0);
            consume(bufc, k);
        }
    }

    // remainder vectors (direct path) + scalar tail
    const int nvec = navail >> 2;
    const f32x4* __restrict__ v4 = (const f32x4*)rsrc;
    for (int i = (nal >> 2) + tid; i < nvec; i += 256) {
        f32x4 x = v4[i];
        finish(x, preN + (i << 2), (f32x4*)(rdst + (i << 2)));
    }
    for (int j = preN + (nvec << 2) + tid; j < V; j += 256) {
        float x = pg * vd[base + j];
        if ((bm[j >> 5] >> (j & 31)) & 1u) x += lookup(j);
        __builtin_nontemporal_store(x, &out[base + j]);
    }
}

// ---------------------------------------------------------------------------
// Fallback (round-1 fused kernel, verified correct) if ws/V/L out of bounds.
// ---------------------------------------------------------------------------
__global__ __launch_bounds__(256) void fused_fallback_kernel(
    const float* __restrict__ vocab_ds, const float* __restrict__ attns,
    const float* __restrict__ p_gens, const int* __restrict__ sources,
    float* __restrict__ out, int V, int L, int B)
{
    const int row = blockIdx.x;
    const int tid = threadIdx.x;
    const size_t base = (size_t)row * (size_t)V;
    const float pg = p_gens[row];

    const int mis  = (int)(base & 3);
    const int pre  = mis ? (4 - mis) : 0;
    const int preN = pre < V ? pre : V;
    for (int j = tid; j < preN; j += blockDim.x)
        out[base + j] = pg * vocab_ds[base + j];
    const int nvec = (V - preN) >> 2;
    const f32x4* __restrict__ v4 = (const f32x4*)(vocab_ds + base + preN);
    f32x4* __restrict__ o4       = (f32x4*)(out + base + preN);
    for (int i = tid; i < nvec; i += blockDim.x) {
        f32x4 x = v4[i];
        x *= pg;
        o4[i] = x;
    }
    for (int j = preN + (nvec << 2) + tid; j < V; j += blockDim.x)
        out[base + j] = pg * vocab_ds[base + j];

    __shared__ int s_src[512];
    const int b = row % B;
    const bool use_lds = (L <= 512);
    if (use_lds) {
        for (int l = tid; l < L; l += blockDim.x)
            s_src[l] = sources[(size_t)l * B + b];
    }
    __syncthreads();
    const float gate = 1.0f - pg;
    for (int l = tid; l < L; l += blockDim.x) {
        const int v = use_lds ? s_src[l] : sources[(size_t)l * B + b];
        if (v < 0 || v >= V) continue;
        bool last = true;
        for (int l2 = l + 1; l2 < L; ++l2) {
            const int v2 = use_lds ? s_src[l2] : sources[(size_t)l2 * B + b];
            if (v2 == v) { last = false; break; }
        }
        if (last) {
            const float a = gate * attns[(size_t)row * L + l];
            out[base + v] = pg * vocab_ds[base + v] + a;
        }
    }
}

extern "C" void kernel_launch(void* const* d_in, const int* in_sizes, int n_in,
                              void* d_out, int out_size, void* d_ws, size_t ws_size,
                              hipStream_t stream) {
    const float* vocab_ds = (const float*)d_in[0];
    const float* attns    = (const float*)d_in[1];
    const float* p_gens   = (const float*)d_in[2];
    const int*   sources  = (const int*)d_in[3];
    const int rows = in_sizes[2];
    const int V    = in_sizes[0] / rows;
    const int L    = in_sizes[1] / rows;
    const int B    = in_sizes[3] / L;
    float* out = (float*)d_out;

    const size_t need = (size_t)B * (size_t)L * 2 * sizeof(int);
    const bool fits = (ws_size >= need) && (V <= (NWMAX - 1) * 32) &&
                      (V <= 65534) && (L <= LP2);
    if (fits) {
        int* sv = (int*)d_ws;
        int* sl = sv + (size_t)B * (size_t)L;
        sort_kernel<<<B, 256, 0, stream>>>(sources, sv, sl, L, B, V);
        fused_kernel<<<rows, 256, 0, stream>>>(vocab_ds, attns, p_gens,
                                               sv, sl, out, V, L, B);
    } else {
        fused_fallback_kernel<<<rows, 256, 0, stream>>>(
            vocab_ds, attns, p_gens, sources, out, V, L, B);
    }
}